// Round 12
// baseline (98.424 us; speedup 1.0000x reference)
//
#include <hip/hip_runtime.h>
#include <math.h>

// Problem constants (B=8, P=64, V=32, N_TH1=30 -> D=1626)
#define NBP 512          // B*P
#define VV 32
#define DD 1626
#define DHALF 813        // directions per block (2 halves)

// Output layout (flat float32, concatenated in return order)
#define O_POINTS 0                         // (8,64*1626,3)  = 2497536
#define O_DIRH   2497536                   // (8,64,1626,4)  = 3330048
#define O_OVER   5827584                   // (8,64,1)       = 512
#define O_RETR   5828096                   // (8,64,1)       = 512
#define O_MEAN   5828608                   // (8,64,3)       = 1536
#define O_LOCAL  5830144                   // (8,64,32,3)    = 49152

#define L10_2 0.3010299956639812f    // log10(2)
#define L2_10 3.321928094887362f     // log2(10)
#define LH_MIN -66.43856189774725f   // log2(1e-20)

__device__ __forceinline__ float fexp2(float x) {
  return __builtin_amdgcn_exp2f(x);    // raw v_exp_f32
}

// inline direction via hardware v_sin/v_cos
__device__ __forceinline__ void make_dir_fast(int d, float& x, float& y, float& z) {
  if (d < 1624) {
    const int i1 = d / 58 + 1;        // 1..28
    const int i2 = d - (i1 - 1) * 58; // 0..57
    const float STEP = 0.10833078115826873f;        // pi/29
    const float th1 = -1.5707963267948966f + (float)i1 * STEP;
    const float th2 = -3.14159265358979323846f + (float)i2 * STEP;
    const float s1 = __sinf(th1);
    const float c1 = __cosf(th1);
    const float s2 = __sinf(th2);
    const float c2 = __cosf(th2);
    x = c1 * c2; y = c1 * s2; z = s1;
  } else if (d == 1624) {             // pole th1=-pi/2 (numpy f64->f32 values)
    x = -6.123234e-17f; y = -7.49880e-33f; z = -1.0f;
  } else {                            // pole th1=+pi/2
    x = -6.123234e-17f; y = -7.49880e-33f; z = 1.0f;
  }
}

__global__ __launch_bounds__(256) void spt_kernel(
    const float* __restrict__ vertices,
    const float* __restrict__ smooth,
    float* __restrict__ out,
    int reps)                          // runtime arg: defeats DSE; always 2
{
  const int bp   = blockIdx.x;   // 0..511
  const int half = blockIdx.y;   // 0..1
  const int tid  = threadIdx.x;

  __shared__ __align__(16) float slvx[VV];
  __shared__ __align__(16) float slvy[VV];
  __shared__ __align__(16) float slvz[VV];

  const int dbase = half * DHALF;

  // ---- wave-redundant mean via shuffle; lv -> LDS; ONE barrier ----
  const int v = tid & 31;
  const float* vp = vertices + bp * (VV * 3) + v * 3;
  const float vx = vp[0], vy = vp[1], vz = vp[2];
  float sx = vx, sy = vy, sz = vz;
#pragma unroll
  for (int m = 16; m >= 1; m >>= 1) {
    sx += __shfl_xor(sx, m);
    sy += __shfl_xor(sy, m);
    sz += __shfl_xor(sz, m);
  }
  const float mx = sx * (1.0f / 32.0f);
  const float my = sy * (1.0f / 32.0f);
  const float mz = sz * (1.0f / 32.0f);
  if (tid < VV) {
    slvx[tid] = vx - mx;
    slvy[tid] = vy - my;
    slvz[tid] = vz - mz;
  }
  __syncthreads();

  // ---- side outputs (once, by half 1) ----
  if (half == 1) {
    if (tid < VV * 3) {
      const int vv = tid / 3, c = tid - vv * 3;
      const float val = (c == 0) ? slvx[vv] : ((c == 1) ? slvy[vv] : slvz[vv]);
      out[O_LOCAL + bp * (VV * 3) + tid] = val;
    }
    if (tid == 96) {
      out[O_MEAN + bp * 3 + 0] = mx;
      out[O_MEAN + bp * 3 + 1] = my;
      out[O_MEAN + bp * 3 + 2] = mz;
      out[O_OVER + bp] = 0.f;
      out[O_RETR + bp] = 0.f;
    }
  }

  const float p     = smooth[bp];
  const float inv_p = 1.0f / p;
  const float pm1   = p - 1.0f;
  const float plt   = p * L10_2;

  const float4* lvx4 = (const float4*)slvx;
  const float4* lvy4 = (const float4*)slvy;
  const float4* lvz4 = (const float4*)slvz;

  auto process = [&](int idx) {
    const int d = dbase + idx;
    float dx, dy, dz;
    make_dir_fast(d, dx, dy, dz);

    // ---- pass 1: zv[i] = relu(lv.dir) ; zmax  (no trans) ----
    float w[VV];                       // holds zv now, w2 later (in place)
    float zmax = 0.f;
#pragma unroll
    for (int j = 0; j < VV / 4; j++) {
      float4 X = lvx4[j], Y = lvy4[j], Z = lvz4[j];
      float z0 = fmaxf(fmaf(X.x, dx, fmaf(Y.x, dy, Z.x * dz)), 0.f);
      float z1 = fmaxf(fmaf(X.y, dx, fmaf(Y.y, dy, Z.y * dz)), 0.f);
      float z2 = fmaxf(fmaf(X.z, dx, fmaf(Y.z, dy, Z.z * dz)), 0.f);
      float z3 = fmaxf(fmaf(X.w, dx, fmaf(Y.w, dy, Z.w * dz)), 0.f);
      w[j * 4 + 0] = z0; w[j * 4 + 1] = z1;
      w[j * 4 + 2] = z2; w[j * 4 + 3] = z3;
      zmax = fmaxf(zmax, fmaxf(fmaxf(z0, z1), fmaxf(z2, z3)));
    }

    // rescale exponent kc (zmax==0 -> log2=-inf -> kc=20)
    const float expo = __log2f(zmax) * plt;
    float kc = 0.f;
    if (expo < -20.f) {
      kc = fminf(fmaxf(ceilf((-15.f - expo) * inv_p), 0.f), 20.f);
    }
    const float kcl = kc * L2_10;      // log2(k)
    const float A   = p * kcl;         // exponent offset for w2

    // ---- pass 2: w2_i = 2^(pm1*log2(zv_i) + p*kcl); zp_i = w2_i*zv_i ----
    float s0 = 0.f, s1 = 0.f, s2 = 0.f, s3 = 0.f;
#pragma unroll
    for (int j = 0; j < VV / 4; j++) {
      float z0 = w[j * 4 + 0], z1 = w[j * 4 + 1];
      float z2 = w[j * 4 + 2], z3 = w[j * 4 + 3];
      float w0 = fexp2(fmaf(pm1, __log2f(z0), A));   // zv=0 -> -inf -> 0
      float w1 = fexp2(fmaf(pm1, __log2f(z1), A));
      float w2 = fexp2(fmaf(pm1, __log2f(z2), A));
      float w3 = fexp2(fmaf(pm1, __log2f(z3), A));
      s0 += w0 * z0;  s1 += w1 * z1;
      s2 += w2 * z2;  s3 += w3 * z3;
      w[j * 4 + 0] = w0; w[j * 4 + 1] = w1;
      w[j * 4 + 2] = w2; w[j * 4 + 3] = w3;
    }
    const float ssum = (s0 + s1) + (s2 + s3);

    float lh = LH_MIN;
    float C2 = 0.f;                    // dhdz_i = w2_i * C2
    if (ssum > 0.f) {
      lh = inv_p * __log2f(ssum);
      C2 = fexp2(-fmaf(pm1, lh, kcl));
    }

    // ---- pass 3: dhdx = C2 * sum w2_i * lv_i  (pure FMAs) ----
    float ax = 0.f, ay = 0.f, az = 0.f;
#pragma unroll
    for (int j = 0; j < VV / 4; j++) {
      float4 X = lvx4[j], Y = lvy4[j], Z = lvz4[j];
      float w0 = w[j * 4 + 0], w1 = w[j * 4 + 1];
      float w2 = w[j * 4 + 2], w3 = w[j * 4 + 3];
      ax = fmaf(w0, X.x, fmaf(w1, X.y, fmaf(w2, X.z, fmaf(w3, X.w, ax))));
      ay = fmaf(w0, Y.x, fmaf(w1, Y.y, fmaf(w2, Y.z, fmaf(w3, Y.w, ay))));
      az = fmaf(w0, Z.x, fmaf(w1, Z.y, fmaf(w2, Z.z, fmaf(w3, Z.w, az))));
    }

    const int pbase = bp * DD + d;
    out[O_POINTS + pbase * 3 + 0] = fmaf(C2, ax, mx);
    out[O_POINTS + pbase * 3 + 1] = fmaf(C2, ay, my);
    out[O_POINTS + pbase * 3 + 2] = fmaf(C2, az, mz);

    // direction_h row as one dwordx4 store (w = h/k)
    float4 dvh = make_float4(dx, dy, dz, fexp2(lh - kcl));
    ((float4*)(out + O_DIRH))[pbase] = dvh;
  };

  // DIAGNOSTIC: run the direction workload `reps` times (host passes 2).
  // Identical idempotent stores; runtime bound prevents dead-store elim.
  for (int r = 0; r < reps; ++r) {
    process(tid);
    process(256 + tid);
    process(512 + tid);
    if (tid < DHALF - 768) process(768 + tid);   // 45 threads
  }
}

extern "C" void kernel_launch(void* const* d_in, const int* in_sizes, int n_in,
                              void* d_out, int out_size, void* d_ws, size_t ws_size,
                              hipStream_t stream) {
  const float* vertices = (const float*)d_in[0];  // (8,64,32,3) f32
  const float* smooth   = (const float*)d_in[1];  // (8,64) f32
  float* out = (float*)d_out;

  spt_kernel<<<dim3(NBP, 2), 256, 0, stream>>>(vertices, smooth, out, 2);
}

// Round 13
// 77.702 us; speedup vs baseline: 1.2667x; 1.2667x over previous
//
#include <hip/hip_runtime.h>
#include <math.h>

// Problem constants (B=8, P=64, V=32, N_TH1=30 -> D=1626)
#define NBP 512          // B*P
#define VV 32
#define DD 1626
#define DSPAN 407        // dirs per block (4 blocks along dir dim)

// Output layout (flat float32, concatenated in return order)
#define O_POINTS 0                         // (8,64*1626,3)  = 2497536
#define O_DIRH   2497536                   // (8,64,1626,4)  = 3330048
#define O_OVER   5827584                   // (8,64,1)       = 512
#define O_RETR   5828096                   // (8,64,1)       = 512
#define O_MEAN   5828608                   // (8,64,3)       = 1536
#define O_LOCAL  5830144                   // (8,64,32,3)    = 49152

#define L10_2 0.3010299956639812f    // log10(2)
#define L2_10 3.321928094887362f     // log2(10)
#define LH_MIN -66.43856189774725f   // log2(1e-20)

__device__ __forceinline__ float fexp2(float x) {
  return __builtin_amdgcn_exp2f(x);    // raw v_exp_f32
}

// inline direction via hardware v_sin/v_cos
__device__ __forceinline__ void make_dir_fast(int d, float& x, float& y, float& z) {
  if (d < 1624) {
    const int i1 = d / 58 + 1;        // 1..28
    const int i2 = d - (i1 - 1) * 58; // 0..57
    const float STEP = 0.10833078115826873f;        // pi/29
    const float th1 = -1.5707963267948966f + (float)i1 * STEP;
    const float th2 = -3.14159265358979323846f + (float)i2 * STEP;
    const float s1 = __sinf(th1);
    const float c1 = __cosf(th1);
    const float s2 = __sinf(th2);
    const float c2 = __cosf(th2);
    x = c1 * c2; y = c1 * s2; z = s1;
  } else if (d == 1624) {             // pole th1=-pi/2 (numpy f64->f32 values)
    x = -6.123234e-17f; y = -7.49880e-33f; z = -1.0f;
  } else {                            // pole th1=+pi/2
    x = -6.123234e-17f; y = -7.49880e-33f; z = 1.0f;
  }
}

// Fused SPT: no per-element array survives across loops -> low VGPR ->
// 8 waves/SIMD. Pass A computes zmax only; pass B recomputes zv from LDS
// and accumulates ssum and the (unscaled) dhdx sums in one sweep.
__global__ __launch_bounds__(256) void spt_kernel(
    const float* __restrict__ vertices,
    const float* __restrict__ smooth,
    float* __restrict__ out)
{
  const int bp  = blockIdx.x;   // 0..511
  const int bz  = blockIdx.y;   // 0..3
  const int tid = threadIdx.x;

  __shared__ __align__(16) float slvx[VV];
  __shared__ __align__(16) float slvy[VV];
  __shared__ __align__(16) float slvz[VV];

  const int dbase = bz * DSPAN;
  const int dend  = (DD - dbase) < DSPAN ? (DD - dbase) : DSPAN;  // 407/405

  // ---- wave-redundant mean via shuffle; lv -> LDS; ONE barrier ----
  const int v = tid & 31;
  const float* vp = vertices + bp * (VV * 3) + v * 3;
  const float vx = vp[0], vy = vp[1], vz = vp[2];
  float sx = vx, sy = vy, sz = vz;
#pragma unroll
  for (int m = 16; m >= 1; m >>= 1) {
    sx += __shfl_xor(sx, m);
    sy += __shfl_xor(sy, m);
    sz += __shfl_xor(sz, m);
  }
  const float mx = sx * (1.0f / 32.0f);
  const float my = sy * (1.0f / 32.0f);
  const float mz = sz * (1.0f / 32.0f);
  if (tid < VV) {
    slvx[tid] = vx - mx;
    slvy[tid] = vy - my;
    slvz[tid] = vz - mz;
  }
  __syncthreads();

  // ---- side outputs (once, by bz==1) ----
  if (bz == 1) {
    if (tid < VV * 3) {
      const int vv = tid / 3, c = tid - vv * 3;
      const float val = (c == 0) ? slvx[vv] : ((c == 1) ? slvy[vv] : slvz[vv]);
      out[O_LOCAL + bp * (VV * 3) + tid] = val;
    }
    if (tid == 96) {
      out[O_MEAN + bp * 3 + 0] = mx;
      out[O_MEAN + bp * 3 + 1] = my;
      out[O_MEAN + bp * 3 + 2] = mz;
      out[O_OVER + bp] = 0.f;
      out[O_RETR + bp] = 0.f;
    }
  }

  const float p     = smooth[bp];
  const float inv_p = 1.0f / p;
  const float pm1   = p - 1.0f;
  const float plt   = p * L10_2;

  const float4* lvx4 = (const float4*)slvx;
  const float4* lvy4 = (const float4*)slvy;
  const float4* lvz4 = (const float4*)slvz;

  auto process = [&](int idx) {
    const int d = dbase + idx;
    float dx, dy, dz;
    make_dir_fast(d, dx, dy, dz);

    // ---- pass A: zmax only (no per-element state kept) ----
    float zmax = 0.f;
#pragma unroll
    for (int j = 0; j < VV / 4; j++) {
      float4 X = lvx4[j], Y = lvy4[j], Z = lvz4[j];
      float z0 = fmaxf(fmaf(X.x, dx, fmaf(Y.x, dy, Z.x * dz)), 0.f);
      float z1 = fmaxf(fmaf(X.y, dx, fmaf(Y.y, dy, Z.y * dz)), 0.f);
      float z2 = fmaxf(fmaf(X.z, dx, fmaf(Y.z, dy, Z.z * dz)), 0.f);
      float z3 = fmaxf(fmaf(X.w, dx, fmaf(Y.w, dy, Z.w * dz)), 0.f);
      zmax = fmaxf(zmax, fmaxf(fmaxf(z0, z1), fmaxf(z2, z3)));
    }

    // rescale exponent kc (zmax==0 -> log2=-inf -> kc=20)
    const float expo = __log2f(zmax) * plt;
    float kc = 0.f;
    if (expo < -20.f) {
      kc = fminf(fmaxf(ceilf((-15.f - expo) * inv_p), 0.f), 20.f);
    }
    const float kcl = kc * L2_10;      // log2(k)
    const float A   = p * kcl;         // exponent offset: u = zv^(p-1) * k^p

    // ---- pass B (fused 2+3): recompute zv; u = 2^(pm1*log2(zv) + A);
    //      ssum += u*zv  (= (zv*k)^p) ;  ax/ay/az += u*lv ----
    float ss0 = 0.f, ss1 = 0.f;
    float ax = 0.f, ay = 0.f, az = 0.f;
#pragma unroll
    for (int j = 0; j < VV / 4; j++) {
      float4 X = lvx4[j], Y = lvy4[j], Z = lvz4[j];
      float z0 = fmaxf(fmaf(X.x, dx, fmaf(Y.x, dy, Z.x * dz)), 0.f);
      float z1 = fmaxf(fmaf(X.y, dx, fmaf(Y.y, dy, Z.y * dz)), 0.f);
      float z2 = fmaxf(fmaf(X.z, dx, fmaf(Y.z, dy, Z.z * dz)), 0.f);
      float z3 = fmaxf(fmaf(X.w, dx, fmaf(Y.w, dy, Z.w * dz)), 0.f);
      float u0 = fexp2(fmaf(pm1, __log2f(z0), A));   // zv=0 -> 0
      float u1 = fexp2(fmaf(pm1, __log2f(z1), A));
      float u2 = fexp2(fmaf(pm1, __log2f(z2), A));
      float u3 = fexp2(fmaf(pm1, __log2f(z3), A));
      ss0 = fmaf(u0, z0, ss0);  ss1 = fmaf(u1, z1, ss1);
      ss0 = fmaf(u2, z2, ss0);  ss1 = fmaf(u3, z3, ss1);
      ax = fmaf(u0, X.x, fmaf(u1, X.y, fmaf(u2, X.z, fmaf(u3, X.w, ax))));
      ay = fmaf(u0, Y.x, fmaf(u1, Y.y, fmaf(u2, Y.z, fmaf(u3, Y.w, ay))));
      az = fmaf(u0, Z.x, fmaf(u1, Z.y, fmaf(u2, Z.z, fmaf(u3, Z.w, az))));
    }
    const float ssum = ss0 + ss1;

    float lh = LH_MIN;
    float C2 = 0.f;                    // dhdz_i = u_i * C2
    if (ssum > 0.f) {
      lh = inv_p * __log2f(ssum);
      C2 = fexp2(-fmaf(pm1, lh, kcl));
    }

    const int pbase = bp * DD + d;
    out[O_POINTS + pbase * 3 + 0] = fmaf(C2, ax, mx);
    out[O_POINTS + pbase * 3 + 1] = fmaf(C2, ay, my);
    out[O_POINTS + pbase * 3 + 2] = fmaf(C2, az, mz);

    // direction_h row as one dwordx4 store (w = h/k)
    float4 dvh = make_float4(dx, dy, dz, fexp2(lh - kcl));
    ((float4*)(out + O_DIRH))[pbase] = dvh;
  };

  process(tid);
  if (tid + 256 < dend) process(256 + tid);    // 151 (bz<3) / 149 (bz=3)
}

extern "C" void kernel_launch(void* const* d_in, const int* in_sizes, int n_in,
                              void* d_out, int out_size, void* d_ws, size_t ws_size,
                              hipStream_t stream) {
  const float* vertices = (const float*)d_in[0];  // (8,64,32,3) f32
  const float* smooth   = (const float*)d_in[1];  // (8,64) f32
  float* out = (float*)d_out;

  spt_kernel<<<dim3(NBP, 4), 256, 0, stream>>>(vertices, smooth, out);
}

// Round 14
// 77.389 us; speedup vs baseline: 1.2718x; 1.0040x over previous
//
#include <hip/hip_runtime.h>
#include <math.h>

// Problem constants (B=8, P=64, V=32, N_TH1=30 -> D=1626)
#define NBP 512          // B*P
#define VV 32
#define DD 1626
#define DHALF 813        // directions per block (2 halves)

// Output layout (flat float32, concatenated in return order)
#define O_POINTS 0                         // (8,64*1626,3)  = 2497536
#define O_DIRH   2497536                   // (8,64,1626,4)  = 3330048
#define O_OVER   5827584                   // (8,64,1)       = 512
#define O_RETR   5828096                   // (8,64,1)       = 512
#define O_MEAN   5828608                   // (8,64,3)       = 1536
#define O_LOCAL  5830144                   // (8,64,32,3)    = 49152

#define L10_2 0.3010299956639812f    // log10(2)
#define L2_10 3.321928094887362f     // log2(10)
#define LH_MIN -66.43856189774725f   // log2(1e-20)

__device__ __forceinline__ float fexp2(float x) {
  return __builtin_amdgcn_exp2f(x);    // raw v_exp_f32
}

// inline direction via hardware v_sin/v_cos
__device__ __forceinline__ void make_dir_fast(int d, float& x, float& y, float& z) {
  if (d < 1624) {
    const int i1 = d / 58 + 1;        // 1..28
    const int i2 = d - (i1 - 1) * 58; // 0..57
    const float STEP = 0.10833078115826873f;        // pi/29
    const float th1 = -1.5707963267948966f + (float)i1 * STEP;
    const float th2 = -3.14159265358979323846f + (float)i2 * STEP;
    const float s1 = __sinf(th1);
    const float c1 = __cosf(th1);
    const float s2 = __sinf(th2);
    const float c2 = __cosf(th2);
    x = c1 * c2; y = c1 * s2; z = s1;
  } else if (d == 1624) {             // pole th1=-pi/2 (numpy f64->f32 values)
    x = -6.123234e-17f; y = -7.49880e-33f; z = -1.0f;
  } else {                            // pole th1=+pi/2
    x = -6.123234e-17f; y = -7.49880e-33f; z = 1.0f;
  }
}

// Register-resident SPT: every thread holds all 32 lv vertices (96 floats)
// in VGPRs. No LDS, no barriers, no shuffles. Inner loop is pure VALU+trans.
__global__ __launch_bounds__(256) void spt_kernel(
    const float* __restrict__ vertices,
    const float* __restrict__ smooth,
    float* __restrict__ out)
{
  const int bp   = blockIdx.x;   // 0..511
  const int half = blockIdx.y;   // 0..1
  const int tid  = threadIdx.x;

  const int dbase = half * DHALF;

  // ---- load all 32 vertices into registers (broadcast float4 loads) ----
  float t[VV * 3];
  {
    const float4* vp4 = (const float4*)(vertices + bp * (VV * 3));
#pragma unroll
    for (int j = 0; j < 24; j++) {
      float4 q = vp4[j];
      t[j * 4 + 0] = q.x; t[j * 4 + 1] = q.y;
      t[j * 4 + 2] = q.z; t[j * 4 + 3] = q.w;
    }
  }

  // ---- mean (each thread computes locally; 2 partial chains per comp) ----
  float mxa = 0.f, mxb = 0.f, mya = 0.f, myb = 0.f, mza = 0.f, mzb = 0.f;
#pragma unroll
  for (int i = 0; i < VV; i += 2) {
    mxa += t[3 * i + 0];  mxb += t[3 * i + 3];
    mya += t[3 * i + 1];  myb += t[3 * i + 4];
    mza += t[3 * i + 2];  mzb += t[3 * i + 5];
  }
  const float mx = (mxa + mxb) * (1.0f / 32.0f);
  const float my = (mya + myb) * (1.0f / 32.0f);
  const float mz = (mza + mzb) * (1.0f / 32.0f);

  // ---- subtract mean in place: t becomes lv ----
#pragma unroll
  for (int i = 0; i < VV; i++) {
    t[3 * i + 0] -= mx;
    t[3 * i + 1] -= my;
    t[3 * i + 2] -= mz;
  }

  // ---- side outputs (once, by half 1, thread 0: 24 float4 stores) ----
  if (half == 1 && tid == 0) {
    float4* lp = (float4*)(out + O_LOCAL + bp * (VV * 3));
#pragma unroll
    for (int j = 0; j < 24; j++) {
      lp[j] = make_float4(t[j * 4 + 0], t[j * 4 + 1], t[j * 4 + 2], t[j * 4 + 3]);
    }
    out[O_MEAN + bp * 3 + 0] = mx;
    out[O_MEAN + bp * 3 + 1] = my;
    out[O_MEAN + bp * 3 + 2] = mz;
    out[O_OVER + bp] = 0.f;
    out[O_RETR + bp] = 0.f;
  }

  const float p     = smooth[bp];
  const float inv_p = 1.0f / p;
  const float pm1   = p - 1.0f;
  const float plt   = p * L10_2;

#pragma unroll 1
  for (int r = 0; r < 4; ++r) {
    const int idx = r * 256 + tid;
    if (idx >= DHALF) break;
    const int d = dbase + idx;
    float dx, dy, dz;
    make_dir_fast(d, dx, dy, dz);

    // ---- pass A: zmax only (register operands, no memory) ----
    float zmax = 0.f;
#pragma unroll
    for (int i = 0; i < VV; i++) {
      float zv = fmaxf(fmaf(t[3*i], dx, fmaf(t[3*i+1], dy, t[3*i+2] * dz)), 0.f);
      zmax = fmaxf(zmax, zv);
    }

    // rescale exponent kc (zmax==0 -> log2=-inf -> kc=20)
    const float expo = __log2f(zmax) * plt;
    float kc = 0.f;
    if (expo < -20.f) {
      kc = fminf(fmaxf(ceilf((-15.f - expo) * inv_p), 0.f), 20.f);
    }
    const float kcl = kc * L2_10;      // log2(k)
    const float A   = p * kcl;         // u_i = zv_i^(p-1) * k^p

    // ---- pass B (fused): u = 2^(pm1*log2(zv)+A); ss += u*zv; a += u*lv ----
    float ss0 = 0.f, ss1 = 0.f;
    float ax = 0.f, ay = 0.f, az = 0.f;
#pragma unroll
    for (int i = 0; i < VV; i += 2) {
      float z0 = fmaxf(fmaf(t[3*i+0], dx, fmaf(t[3*i+1], dy, t[3*i+2] * dz)), 0.f);
      float z1 = fmaxf(fmaf(t[3*i+3], dx, fmaf(t[3*i+4], dy, t[3*i+5] * dz)), 0.f);
      float u0 = fexp2(fmaf(pm1, __log2f(z0), A));   // zv=0 -> 0
      float u1 = fexp2(fmaf(pm1, __log2f(z1), A));
      ss0 = fmaf(u0, z0, ss0);
      ss1 = fmaf(u1, z1, ss1);
      ax = fmaf(u0, t[3*i+0], fmaf(u1, t[3*i+3], ax));
      ay = fmaf(u0, t[3*i+1], fmaf(u1, t[3*i+4], ay));
      az = fmaf(u0, t[3*i+2], fmaf(u1, t[3*i+5], az));
    }
    const float ssum = ss0 + ss1;

    float lh = LH_MIN;
    float C2 = 0.f;                    // dhdz_i = u_i * C2
    if (ssum > 0.f) {
      lh = inv_p * __log2f(ssum);
      C2 = fexp2(-fmaf(pm1, lh, kcl));
    }

    const int pbase = bp * DD + d;
    out[O_POINTS + pbase * 3 + 0] = fmaf(C2, ax, mx);
    out[O_POINTS + pbase * 3 + 1] = fmaf(C2, ay, my);
    out[O_POINTS + pbase * 3 + 2] = fmaf(C2, az, mz);

    // direction_h row as one dwordx4 store (w = h/k)
    float4 dvh = make_float4(dx, dy, dz, fexp2(lh - kcl));
    ((float4*)(out + O_DIRH))[pbase] = dvh;
  }
}

extern "C" void kernel_launch(void* const* d_in, const int* in_sizes, int n_in,
                              void* d_out, int out_size, void* d_ws, size_t ws_size,
                              hipStream_t stream) {
  const float* vertices = (const float*)d_in[0];  // (8,64,32,3) f32
  const float* smooth   = (const float*)d_in[1];  // (8,64) f32
  float* out = (float*)d_out;

  spt_kernel<<<dim3(NBP, 2), 256, 0, stream>>>(vertices, smooth, out);
}